// Round 10
// baseline (3313.598 us; speedup 1.0000x reference)
//
#include <hip/hip_runtime.h>
#include <hip/hip_cooperative_groups.h>
#include <cmath>

namespace cg = cooperative_groups;

#define TBUF 1024
#define RCH  256

typedef __bf16 bf16x8 __attribute__((ext_vector_type(8)));
typedef float  f32x4  __attribute__((ext_vector_type(4)));

__device__ inline unsigned short f2bf(float f) {
  unsigned u = __builtin_bit_cast(unsigned, f);
  u += 0x7FFFu + ((u >> 16) & 1u);
  return (unsigned short)(u >> 16);
}

// ---------------- weight transforms ----------------
__global__ __launch_bounds__(256) void transform_fgb(
    const float* __restrict__ wf, const float* __restrict__ wg, unsigned short* __restrict__ Wb)
{
  int idx = blockIdx.x * 256 + threadIdx.x;      // < 32*512*256
  int c  = idx & 255;
  int op = (idx >> 8) & 511;
  int i  = idx >> 17;
  int o  = op & 255;
  const float* src = (op < 256) ? wf : wg;
  const float2 v = *(const float2*)&src[(((size_t)i * 256 + o) * 256 + c) << 1];
  unsigned short* dst = Wb + ((size_t)i * 512 + op) * 512;
  dst[c]       = f2bf(v.y);   // current tap (k=1)
  dst[256 + c] = f2bf(v.x);   // previous tap (k=0)
}

__global__ __launch_bounds__(256) void transform_resb(
    const float* __restrict__ wr, unsigned short* __restrict__ Wrb)
{
  int idx = blockIdx.x * 256 + threadIdx.x;    // < 32*256*256/4
  float4 v = ((const float4*)wr)[idx];
  uint2 o;
  o.x = (unsigned)f2bf(v.x) | ((unsigned)f2bf(v.y) << 16);
  o.y = (unsigned)f2bf(v.z) | ((unsigned)f2bf(v.w) << 16);
  ((uint2*)Wrb)[idx] = o;
}

__global__ __launch_bounds__(256) void transform_skip(
    const float* __restrict__ wsk, float* __restrict__ wskT)
{
  int idx = blockIdx.x * 256 + threadIdx.x;    // < 32*256*128
  int s = idx & 127;
  int c = (idx >> 7) & 255;
  int i = idx >> 15;
  wskT[idx] = wsk[(i * 128 + s) * 256 + c];
}

__global__ __launch_bounds__(256) void transform_w2(
    const float* __restrict__ w_in, float* __restrict__ w2)
{
  int idx = blockIdx.x * 256 + threadIdx.x;    // < 64*256
  int r = idx & 255;
  int fk = idx >> 8;
  int f = fk & 31, k = fk >> 5;
  w2[idx] = w_in[r * 64 + f * 2 + k];
}

// ---------------- input conv (F=32 -> R=256, K=2, d=1) ----------------
__global__ __launch_bounds__(256) void in_conv(
    const float* __restrict__ X, const float* __restrict__ w2,
    const float* __restrict__ b_in, float* __restrict__ xb,
    unsigned short* __restrict__ xbb)
{
  const int bid   = blockIdx.x;
  const int b     = bid & 15;
  const int chunk = bid >> 4;
  const int r     = threadIdx.x;
  __shared__ float Xs[17][32];
  const int tt0 = chunk << 4;
  const int t0  = tt0 + 1024;
  for (int idx = r; idx < 17 * 32; idx += 256) {
    int row = idx >> 5, f = idx & 31;
    Xs[row][f] = X[((size_t)b * 2048 + (t0 - 1 + row)) * 32 + f];
  }
  __syncthreads();
  float w0[32], w1[32];
  #pragma unroll
  for (int f = 0; f < 32; ++f) {
    w0[f] = w2[f * 256 + r];
    w1[f] = w2[(32 + f) * 256 + r];
  }
  const float bias = b_in[r];
  float4 prev[8], cur[8];
  #pragma unroll
  for (int q = 0; q < 8; ++q) prev[q] = *(const float4*)&Xs[0][q * 4];
  #pragma unroll
  for (int j = 0; j < 16; ++j) {
    #pragma unroll
    for (int q = 0; q < 8; ++q) cur[q] = *(const float4*)&Xs[j + 1][q * 4];
    float a = bias;
    #pragma unroll
    for (int q = 0; q < 8; ++q) {
      a = fmaf(w0[q*4+0], prev[q].x, a); a = fmaf(w1[q*4+0], cur[q].x, a);
      a = fmaf(w0[q*4+1], prev[q].y, a); a = fmaf(w1[q*4+1], cur[q].y, a);
      a = fmaf(w0[q*4+2], prev[q].z, a); a = fmaf(w1[q*4+2], cur[q].z, a);
      a = fmaf(w0[q*4+3], prev[q].w, a); a = fmaf(w1[q*4+3], cur[q].w, a);
    }
    int tt = tt0 + j;
    size_t off = ((size_t)b * TBUF + tt) * RCH + r;
    if (tt < 3) { xb[off] = 0.f; xbb[off] = 0; }
    else        { xb[off] = a;   xbb[off] = f2bf(a); }
    #pragma unroll
    for (int q = 0; q < 8; ++q) prev[q] = cur[q];
  }
}

// ---------------- persistent all-layers kernel ----------------
// 256 blocks x 512 thr (8 waves), co-resident (1 block/CU). Per layer:
// block (tile = bid>>4, b = bid&15) runs the r9-proven fused body on its
// 64-row tile, then grid.sync(). No per-layer dispatch/ramp cost; x stays
// L2-warm across layers (batch-pinned blocks).
__global__ __launch_bounds__(512, 2) void layers_persistent(
    unsigned short* __restrict__ xbbA, float* __restrict__ xb,
    unsigned short* __restrict__ xbbB,
    const unsigned short* __restrict__ Wb_all,
    const unsigned short* __restrict__ Wrb_all,
    const float* __restrict__ bF_all, const float* __restrict__ bG_all,
    const float* __restrict__ bR_all, float* __restrict__ fxs)
{
  static const int wI[33] = {1021,1020,1018,1014,1006,990,958,894,
                             766,765,763,759,751,735,703,639,
                             511,510,508,504,496,480,448,384,
                             256,255,253,249,241,225,193,129,1};
  __shared__ __align__(16) unsigned short As[64 * 520];   // 66,560 B; z aliases
  cg::grid_group grid = cg::this_grid();

  const int bid  = blockIdx.x;
  const int b    = bid & 15;
  const int tile = bid >> 4;
  const int tid  = threadIdx.x;
  const int w    = tid >> 6;
  const int lane = tid & 63;
  const int l15  = lane & 15;
  const int lk8  = (lane >> 4) << 3;
  const int rr0  = (lane >> 4) << 2;

  #pragma unroll 1
  for (int i = 0; i < 32; ++i) {
    const int dd    = 1 << (i & 7);
    const int Wout  = wI[i + 1];
    const int t_lo  = TBUF - Wout;
    const int tiles = (Wout + 63) >> 6;
    const unsigned short* xbb_r = (i & 1) ? xbbB : xbbA;
    unsigned short*       xbb_w = (i & 1) ? xbbA : xbbB;
    const unsigned short* Wb  = Wb_all  + ((size_t)i << 18);
    const unsigned short* Wrb = Wrb_all + ((size_t)i << 16);
    const float* bF = bF_all + (i << 8);
    const float* bG = bG_all + (i << 8);
    const float* bR = bR_all + (i << 8);
    float* fxs_i = fxs + ((size_t)i << 12);

    if (tile < tiles) {
      const int tt0 = t_lo + tile * 64;
      const unsigned short* xB = xbb_r + ((size_t)b << 18);

      // ---- stage A tile: 64 rows x 512 k (k<256: x[tt], k>=256: x[tt-d])
      #pragma unroll
      for (int it = 0; it < 8; ++it) {
        int flat = it * 512 + tid;
        int r = flat >> 6;
        int c = flat & 63;
        int tap = c >> 5;
        int tt = tt0 + r - tap * dd;
        tt = min(max(tt, 0), 1023);
        uint4 v = *(const uint4*)&xB[((size_t)tt << 8) + ((c & 31) << 3)];
        *(uint4*)((char*)As + r * 1040 + (c << 4)) = v;
      }
      __syncthreads();

      // ---- conv GEMM: per wave 64(M) x {32 f + 32 g}
      f32x4 accf[4][2] = {};
      f32x4 accg[4][2] = {};
      const unsigned short* wf0 = Wb + (size_t)(32 * w + l15) * 512 + lk8;
      const unsigned short* wf1 = wf0 + (size_t)16 * 512;
      const unsigned short* wg0 = wf0 + (size_t)256 * 512;
      const unsigned short* wg1 = wf0 + (size_t)272 * 512;
      #pragma unroll 4
      for (int kc = 0; kc < 16; ++kc) {
        const int k0 = kc * 32;
        uint4 ubf0 = *(const uint4*)(wf0 + k0);
        uint4 ubf1 = *(const uint4*)(wf1 + k0);
        uint4 ubg0 = *(const uint4*)(wg0 + k0);
        uint4 ubg1 = *(const uint4*)(wg1 + k0);
        const int colb = (k0 + lk8) * 2;
        bf16x8 a[4];
        #pragma unroll
        for (int mf = 0; mf < 4; ++mf)
          a[mf] = *(const bf16x8*)((const char*)As + (mf * 16 + l15) * 1040 + colb);
        bf16x8 vf0 = __builtin_bit_cast(bf16x8, ubf0);
        bf16x8 vf1 = __builtin_bit_cast(bf16x8, ubf1);
        bf16x8 vg0 = __builtin_bit_cast(bf16x8, ubg0);
        bf16x8 vg1 = __builtin_bit_cast(bf16x8, ubg1);
        #pragma unroll
        for (int mf = 0; mf < 4; ++mf) {
          accf[mf][0] = __builtin_amdgcn_mfma_f32_16x16x32_bf16(a[mf], vf0, accf[mf][0], 0, 0, 0);
          accf[mf][1] = __builtin_amdgcn_mfma_f32_16x16x32_bf16(a[mf], vf1, accf[mf][1], 0, 0, 0);
          accg[mf][0] = __builtin_amdgcn_mfma_f32_16x16x32_bf16(a[mf], vg0, accg[mf][0], 0, 0, 0);
          accg[mf][1] = __builtin_amdgcn_mfma_f32_16x16x32_bf16(a[mf], vg1, accg[mf][1], 0, 0, 0);
        }
      }
      __syncthreads();

      // ---- gate epilogue -> z in LDS (aliased)
      unsigned short* Zs = As;
      const float bfv[2] = { bF[32 * w + l15], bF[32 * w + 16 + l15] };
      const float bgv[2] = { bG[32 * w + l15], bG[32 * w + 16 + l15] };
      #pragma unroll
      for (int mf = 0; mf < 4; ++mf)
        #pragma unroll
        for (int nf = 0; nf < 2; ++nf) {
          int col = 32 * w + nf * 16 + l15;
          #pragma unroll
          for (int j = 0; j < 4; ++j) {
            int row = mf * 16 + rr0 + j;
            float pf = accf[mf][nf][j] + bfv[nf];
            float pg = accg[mf][nf][j] + bgv[nf];
            float e2 = __expf(2.f * pf);
            float th = 1.f - 2.f / (e2 + 1.f);
            float sg = 1.f / (1.f + __expf(-pg));
            *(unsigned short*)((char*)Zs + row * 528 + col * 2) = f2bf(th * sg);
          }
        }
      __syncthreads();

      // ---- res GEMM: per wave 64(M) x 32(N), K=256 (B loads in-loop)
      f32x4 acc[4][2] = {};
      const unsigned short* wr0 = Wrb + (size_t)(32 * w + l15) * 256 + lk8;
      const unsigned short* wr1 = wr0 + (size_t)16 * 256;
      #pragma unroll 4
      for (int kc = 0; kc < 8; ++kc) {
        uint4 ur0 = *(const uint4*)(wr0 + kc * 32);
        uint4 ur1 = *(const uint4*)(wr1 + kc * 32);
        const int colb = (kc * 32 + lk8) * 2;
        bf16x8 a[4];
        #pragma unroll
        for (int mf = 0; mf < 4; ++mf)
          a[mf] = *(const bf16x8*)((const char*)Zs + (mf * 16 + l15) * 528 + colb);
        bf16x8 v0 = __builtin_bit_cast(bf16x8, ur0);
        bf16x8 v1 = __builtin_bit_cast(bf16x8, ur1);
        #pragma unroll
        for (int mf = 0; mf < 4; ++mf) {
          acc[mf][0] = __builtin_amdgcn_mfma_f32_16x16x32_bf16(a[mf], v0, acc[mf][0], 0, 0, 0);
          acc[mf][1] = __builtin_amdgcn_mfma_f32_16x16x32_bf16(a[mf], v1, acc[mf][1], 0, 0, 0);
        }
      }

      // ---- residual epilogue
      const float brv[2] = { bR[32 * w + l15], bR[32 * w + 16 + l15] };
      float* xBf = xb + ((size_t)b << 18);
      unsigned short* xBb = xbb_w + ((size_t)b << 18);
      #pragma unroll
      for (int mf = 0; mf < 4; ++mf)
        #pragma unroll
        for (int j = 0; j < 4; ++j) {
          int tt = tt0 + mf * 16 + rr0 + j;
          if (tt > 1023) continue;
          #pragma unroll
          for (int nf = 0; nf < 2; ++nf) {
            int o = 32 * w + nf * 16 + l15;
            size_t off = ((size_t)tt << 8) + o;
            float fx = acc[mf][nf][j] + brv[nf];
            float xn = xBf[off] + fx;
            xBf[off] = xn;
            xBb[off] = f2bf(xn);
            if (tt == 1023) fxs_i[(size_t)b * 256 + o] = fx;
          }
        }
      __syncthreads();   // protect As before next layer's staging
    }
    __threadfence();
    grid.sync();
  }
}

// ---------------- head ----------------
__global__ __launch_bounds__(128) void skip_partial(
    const float* __restrict__ fxs, const float* __restrict__ wskT,
    const float* __restrict__ b_skip, float* __restrict__ part)
{
  int i = blockIdx.x, b = blockIdx.y, s = threadIdx.x;
  __shared__ float fxsh[256];
  fxsh[s]       = fxs[((size_t)i * 16 + b) * 256 + s];
  fxsh[s + 128] = fxs[((size_t)i * 16 + b) * 256 + s + 128];
  __syncthreads();
  float a = b_skip[i * 128 + s];
  const float* wp = wskT + (size_t)i * 256 * 128 + s;
  #pragma unroll 4
  for (int c = 0; c < 256; c++)
    a = fmaf(wp[c * 128], fxsh[c], a);
  part[((size_t)i * 16 + b) * 128 + s] = a;
}

__global__ __launch_bounds__(128) void head2(
    const float* __restrict__ part, const float* __restrict__ w_o1,
    const float* __restrict__ b_o1, const float* __restrict__ w_o2,
    const float* __restrict__ b_o2, const float* __restrict__ w_lin,
    const float* __restrict__ b_lin, const float* __restrict__ Xex,
    float* __restrict__ out)
{
  int b = blockIdx.x, tid = threadIdx.x;
  __shared__ float sk[128];
  __shared__ float h1[64];
  __shared__ float hc[80];
  float a = 0.f;
  for (int i = 0; i < 32; i++) a += part[((size_t)i * 16 + b) * 128 + tid];
  sk[tid] = fmaxf(a, 0.f);
  __syncthreads();
  if (tid < 64) {
    float a1 = b_o1[tid];
    for (int s = 0; s < 128; s++) a1 = fmaf(w_o1[tid * 128 + s], sk[s], a1);
    h1[tid] = fmaxf(a1, 0.f);
  }
  __syncthreads();
  if (tid < 64) {
    float a2 = b_o2[tid];
    for (int j = 0; j < 64; j++) a2 = fmaf(w_o2[tid * 64 + j], h1[j], a2);
    hc[tid] = fmaxf(a2, 0.f);
  }
  if (tid >= 64 && tid < 80) hc[tid] = fmaxf(Xex[b * 16 + (tid - 64)], 0.f);
  __syncthreads();
  if (tid < 24) {
    float a3 = b_lin[tid];
    for (int j = 0; j < 80; j++) a3 = fmaf(w_lin[tid * 80 + j], hc[j], a3);
    out[b * 24 + tid] = a3;
  }
}

extern "C" void kernel_launch(void* const* d_in, const int* in_sizes, int n_in,
                              void* d_out, int out_size, void* d_ws, size_t ws_size,
                              hipStream_t stream)
{
  (void)in_sizes; (void)n_in; (void)out_size; (void)ws_size;
  const float* X     = (const float*)d_in[0];
  const float* Xex   = (const float*)d_in[1];
  const float* w_in  = (const float*)d_in[2];
  const float* b_in  = (const float*)d_in[3];
  const float* w_f   = (const float*)d_in[4];
  const float* b_f   = (const float*)d_in[5];
  const float* w_g   = (const float*)d_in[6];
  const float* b_g   = (const float*)d_in[7];
  const float* w_r   = (const float*)d_in[8];
  const float* b_r   = (const float*)d_in[9];
  const float* w_s   = (const float*)d_in[10];
  const float* b_s   = (const float*)d_in[11];
  const float* w_o1  = (const float*)d_in[12];
  const float* b_o1  = (const float*)d_in[13];
  const float* w_o2  = (const float*)d_in[14];
  const float* b_o2  = (const float*)d_in[15];
  const float* w_lin = (const float*)d_in[16];
  const float* b_lin = (const float*)d_in[17];

  float* ws   = (float*)d_ws;
  float* wskT = ws;                        // 1,048,576 f
  float* xb   = wskT + 1048576;            // 4,194,304 f
  float* fxs  = xb   + 4194304;            // 131,072 f
  float* part = fxs  + 131072;             // 65,536 f
  float* w2   = part + 65536;              // 16,384 f
  unsigned short* Wb   = (unsigned short*)(w2 + 16384);    // 8,388,608 us
  unsigned short* Wrb  = Wb   + 8388608;   // 2,097,152 us
  unsigned short* xbbA = Wrb  + 2097152;   // 4,194,304 us
  unsigned short* xbbB = xbbA + 4194304;   // 4,194,304 us

  transform_fgb <<<16384, 256, 0, stream>>>(w_f, w_g, Wb);
  transform_resb<<<2048,  256, 0, stream>>>(w_r, Wrb);
  transform_skip<<<4096,  256, 0, stream>>>(w_s, wskT);
  transform_w2  <<<64,    256, 0, stream>>>(w_in, w2);
  in_conv<<<1024, 256, 0, stream>>>(X, w2, b_in, xb, xbbA);

  {
    void* args[] = { (void*)&xbbA, (void*)&xb, (void*)&xbbB,
                     (void*)&Wb, (void*)&Wrb,
                     (void*)&b_f, (void*)&b_g, (void*)&b_r, (void*)&fxs };
    hipLaunchCooperativeKernel((const void*)layers_persistent,
                               dim3(256), dim3(512), args, 0, stream);
  }

  skip_partial<<<dim3(32, 16), 128, 0, stream>>>(fxs, wskT, b_s, part);
  head2<<<16, 128, 0, stream>>>(part, w_o1, b_o1, w_o2, b_o2, w_lin, b_lin, Xex, (float*)d_out);
}

// Round 11
// 1025.433 us; speedup vs baseline: 3.2314x; 3.2314x over previous
//
#include <hip/hip_runtime.h>
#include <cmath>

#define TBUF 1024
#define RCH  256

typedef __bf16 bf16x8 __attribute__((ext_vector_type(8)));
typedef float  f32x4  __attribute__((ext_vector_type(4)));

__device__ inline unsigned short f2bf(float f) {
  unsigned u = __builtin_bit_cast(unsigned, f);
  u += 0x7FFFu + ((u >> 16) & 1u);
  return (unsigned short)(u >> 16);
}

// ---------------- weight transforms ----------------
__global__ __launch_bounds__(256) void transform_fgb(
    const float* __restrict__ wf, const float* __restrict__ wg, unsigned short* __restrict__ Wb)
{
  int idx = blockIdx.x * 256 + threadIdx.x;      // < 32*512*256
  int c  = idx & 255;
  int op = (idx >> 8) & 511;
  int i  = idx >> 17;
  int o  = op & 255;
  const float* src = (op < 256) ? wf : wg;
  const float2 v = *(const float2*)&src[(((size_t)i * 256 + o) * 256 + c) << 1];
  unsigned short* dst = Wb + ((size_t)i * 512 + op) * 512;
  dst[c]       = f2bf(v.y);   // current tap (k=1)
  dst[256 + c] = f2bf(v.x);   // previous tap (k=0)
}

__global__ __launch_bounds__(256) void transform_resb(
    const float* __restrict__ wr, unsigned short* __restrict__ Wrb)
{
  int idx = blockIdx.x * 256 + threadIdx.x;    // < 32*256*256/4
  float4 v = ((const float4*)wr)[idx];
  uint2 o;
  o.x = (unsigned)f2bf(v.x) | ((unsigned)f2bf(v.y) << 16);
  o.y = (unsigned)f2bf(v.z) | ((unsigned)f2bf(v.w) << 16);
  ((uint2*)Wrb)[idx] = o;
}

__global__ __launch_bounds__(256) void transform_skip(
    const float* __restrict__ wsk, float* __restrict__ wskT)
{
  int idx = blockIdx.x * 256 + threadIdx.x;    // < 32*256*128
  int s = idx & 127;
  int c = (idx >> 7) & 255;
  int i = idx >> 15;
  wskT[idx] = wsk[(i * 128 + s) * 256 + c];
}

__global__ __launch_bounds__(256) void transform_w2(
    const float* __restrict__ w_in, float* __restrict__ w2)
{
  int idx = blockIdx.x * 256 + threadIdx.x;    // < 64*256
  int r = idx & 255;
  int fk = idx >> 8;
  int f = fk & 31, k = fk >> 5;
  w2[idx] = w_in[r * 64 + f * 2 + k];
}

// ---------------- input conv (F=32 -> R=256, K=2, d=1) ----------------
__global__ __launch_bounds__(256) void in_conv(
    const float* __restrict__ X, const float* __restrict__ w2,
    const float* __restrict__ b_in, float* __restrict__ xb,
    unsigned short* __restrict__ xbb)
{
  const int bid   = blockIdx.x;
  const int b     = bid & 15;
  const int chunk = bid >> 4;
  const int r     = threadIdx.x;
  __shared__ float Xs[17][32];
  const int tt0 = chunk << 4;
  const int t0  = tt0 + 1024;
  for (int idx = r; idx < 17 * 32; idx += 256) {
    int row = idx >> 5, f = idx & 31;
    Xs[row][f] = X[((size_t)b * 2048 + (t0 - 1 + row)) * 32 + f];
  }
  __syncthreads();
  float w0[32], w1[32];
  #pragma unroll
  for (int f = 0; f < 32; ++f) {
    w0[f] = w2[f * 256 + r];
    w1[f] = w2[(32 + f) * 256 + r];
  }
  const float bias = b_in[r];
  float4 prev[8], cur[8];
  #pragma unroll
  for (int q = 0; q < 8; ++q) prev[q] = *(const float4*)&Xs[0][q * 4];
  #pragma unroll
  for (int j = 0; j < 16; ++j) {
    #pragma unroll
    for (int q = 0; q < 8; ++q) cur[q] = *(const float4*)&Xs[j + 1][q * 4];
    float a = bias;
    #pragma unroll
    for (int q = 0; q < 8; ++q) {
      a = fmaf(w0[q*4+0], prev[q].x, a); a = fmaf(w1[q*4+0], cur[q].x, a);
      a = fmaf(w0[q*4+1], prev[q].y, a); a = fmaf(w1[q*4+1], cur[q].y, a);
      a = fmaf(w0[q*4+2], prev[q].z, a); a = fmaf(w1[q*4+2], cur[q].z, a);
      a = fmaf(w0[q*4+3], prev[q].w, a); a = fmaf(w1[q*4+3], cur[q].w, a);
    }
    int tt = tt0 + j;
    size_t off = ((size_t)b * TBUF + tt) * RCH + r;
    if (tt < 3) { xb[off] = 0.f; xbb[off] = 0; }
    else        { xb[off] = a;   xbb[off] = f2bf(a); }
    #pragma unroll
    for (int q = 0; q < 8; ++q) prev[q] = cur[q];
  }
}

// ---------------- fused layer (r9 body + gload_lds stage + epilogue-load hoist) --------
// 512 thr = 8 waves, M=64 rows, full N. A-tile staged via global_load_lds
// (dest = wave-uniform row base + lane*16 — exact HW contract). Res-B in-loop
// (r4/r8: hoisting res-B across conv spills). fp32-master epilogue loads hoisted
// above the res K-loop (conv accs dead there; ~90 VGPR peak < 128 budget).
__global__ __launch_bounds__(512, 4) void layer_fused(
    const unsigned short* __restrict__ xbb_r, float* __restrict__ xb,
    unsigned short* __restrict__ xbb_w,
    const unsigned short* __restrict__ Wb,   // [512][512] bf16
    const unsigned short* __restrict__ Wrb,  // [256][256] bf16
    const float* __restrict__ bF, const float* __restrict__ bG,
    const float* __restrict__ bR,
    int dd, int t_lo, float* __restrict__ fxs_i)
{
  __shared__ __align__(16) unsigned short As[64 * 520];   // 66,560 B; z aliases
  const int bid  = blockIdx.x;
  const int b    = bid & 15;
  const int tile = bid >> 4;
  const int tid  = threadIdx.x;
  const int w    = tid >> 6;
  const int lane = tid & 63;
  const int l15  = lane & 15;
  const int lk8  = (lane >> 4) << 3;
  const int rr0  = (lane >> 4) << 2;
  const int tt0  = t_lo + tile * 64;
  const unsigned short* xB = xbb_r + ((size_t)b << 18);

  // ---- stage A tile via global_load_lds: 64 rows x 512 k
  //      row r wave-uniform; lane c: tap=c>>5, 16B chunk (c&31)
  {
    const int c   = lane;
    const int tap = c >> 5;
    const int cg  = (c & 31) << 3;
    #pragma unroll
    for (int it = 0; it < 8; ++it) {
      int r = it * 8 + w;
      int tt = tt0 + r - tap * dd;
      tt = min(max(tt, 0), 1023);
      __builtin_amdgcn_global_load_lds(
          (const __attribute__((address_space(1))) unsigned int*)
              (xB + ((size_t)tt << 8) + cg),
          (__attribute__((address_space(3))) unsigned int*)
              ((char*)As + r * 1040),
          16, 0, 0);
    }
  }
  __syncthreads();

  // ---- conv GEMM (no barriers): per wave 64(M) x {32 f + 32 g}
  f32x4 accf[4][2] = {};
  f32x4 accg[4][2] = {};
  const unsigned short* wf0 = Wb + (size_t)(32 * w + l15) * 512 + lk8;
  const unsigned short* wf1 = wf0 + (size_t)16 * 512;
  const unsigned short* wg0 = wf0 + (size_t)256 * 512;
  const unsigned short* wg1 = wf0 + (size_t)272 * 512;
  #pragma unroll 4
  for (int kc = 0; kc < 16; ++kc) {
    const int k0 = kc * 32;
    uint4 ubf0 = *(const uint4*)(wf0 + k0);
    uint4 ubf1 = *(const uint4*)(wf1 + k0);
    uint4 ubg0 = *(const uint4*)(wg0 + k0);
    uint4 ubg1 = *(const uint4*)(wg1 + k0);
    const int colb = (k0 + lk8) * 2;
    bf16x8 a[4];
    #pragma unroll
    for (int mf = 0; mf < 4; ++mf)
      a[mf] = *(const bf16x8*)((const char*)As + (mf * 16 + l15) * 1040 + colb);
    bf16x8 vf0 = __builtin_bit_cast(bf16x8, ubf0);
    bf16x8 vf1 = __builtin_bit_cast(bf16x8, ubf1);
    bf16x8 vg0 = __builtin_bit_cast(bf16x8, ubg0);
    bf16x8 vg1 = __builtin_bit_cast(bf16x8, ubg1);
    #pragma unroll
    for (int mf = 0; mf < 4; ++mf) {
      accf[mf][0] = __builtin_amdgcn_mfma_f32_16x16x32_bf16(a[mf], vf0, accf[mf][0], 0, 0, 0);
      accf[mf][1] = __builtin_amdgcn_mfma_f32_16x16x32_bf16(a[mf], vf1, accf[mf][1], 0, 0, 0);
      accg[mf][0] = __builtin_amdgcn_mfma_f32_16x16x32_bf16(a[mf], vg0, accg[mf][0], 0, 0, 0);
      accg[mf][1] = __builtin_amdgcn_mfma_f32_16x16x32_bf16(a[mf], vg1, accg[mf][1], 0, 0, 0);
    }
  }
  __syncthreads();   // all As reads done -> safe to overwrite with z

  // ---- gate epilogue: z = tanh(f+bf) * sigmoid(g+bg) -> LDS (aliased)
  unsigned short* Zs = As;
  const float bfv[2] = { bF[32 * w + l15], bF[32 * w + 16 + l15] };
  const float bgv[2] = { bG[32 * w + l15], bG[32 * w + 16 + l15] };
  #pragma unroll
  for (int mf = 0; mf < 4; ++mf)
    #pragma unroll
    for (int nf = 0; nf < 2; ++nf) {
      int col = 32 * w + nf * 16 + l15;
      #pragma unroll
      for (int j = 0; j < 4; ++j) {
        int row = mf * 16 + rr0 + j;
        float pf = accf[mf][nf][j] + bfv[nf];
        float pg = accg[mf][nf][j] + bgv[nf];
        float e2 = __expf(2.f * pf);
        float th = 1.f - 2.f / (e2 + 1.f);
        float sg = 1.f / (1.f + __expf(-pg));
        *(unsigned short*)((char*)Zs + row * 528 + col * 2) = f2bf(th * sg);
      }
    }
  __syncthreads();

  // ---- hoist fp32-master loads (independent of z; latency hides under res GEMM)
  float* xBf = xb + ((size_t)b << 18);
  float xo_pre[4][4][2];
  #pragma unroll
  for (int mf = 0; mf < 4; ++mf)
    #pragma unroll
    for (int j = 0; j < 4; ++j) {
      int tt = min(tt0 + mf * 16 + rr0 + j, 1023);
      #pragma unroll
      for (int nf = 0; nf < 2; ++nf) {
        int o = 32 * w + nf * 16 + l15;
        xo_pre[mf][j][nf] = xBf[((size_t)tt << 8) + o];
      }
    }

  // ---- res GEMM: per wave 64(M) x 32(N), K=256 from z-LDS (B loads in-loop)
  f32x4 acc[4][2] = {};
  const unsigned short* wr0 = Wrb + (size_t)(32 * w + l15) * 256 + lk8;
  const unsigned short* wr1 = wr0 + (size_t)16 * 256;
  #pragma unroll 4
  for (int kc = 0; kc < 8; ++kc) {
    uint4 ur0 = *(const uint4*)(wr0 + kc * 32);
    uint4 ur1 = *(const uint4*)(wr1 + kc * 32);
    const int colb = (kc * 32 + lk8) * 2;
    bf16x8 a[4];
    #pragma unroll
    for (int mf = 0; mf < 4; ++mf)
      a[mf] = *(const bf16x8*)((const char*)Zs + (mf * 16 + l15) * 528 + colb);
    bf16x8 v0 = __builtin_bit_cast(bf16x8, ur0);
    bf16x8 v1 = __builtin_bit_cast(bf16x8, ur1);
    #pragma unroll
    for (int mf = 0; mf < 4; ++mf) {
      acc[mf][0] = __builtin_amdgcn_mfma_f32_16x16x32_bf16(a[mf], v0, acc[mf][0], 0, 0, 0);
      acc[mf][1] = __builtin_amdgcn_mfma_f32_16x16x32_bf16(a[mf], v1, acc[mf][1], 0, 0, 0);
    }
  }

  // ---- residual epilogue: fx = acc + bR; x += fx; bf16 mirror; fx snapshot
  const float brv[2] = { bR[32 * w + l15], bR[32 * w + 16 + l15] };
  unsigned short* xBb = xbb_w + ((size_t)b << 18);
  #pragma unroll
  for (int mf = 0; mf < 4; ++mf)
    #pragma unroll
    for (int j = 0; j < 4; ++j) {
      int tt = tt0 + mf * 16 + rr0 + j;
      if (tt > 1023) continue;
      #pragma unroll
      for (int nf = 0; nf < 2; ++nf) {
        int o = 32 * w + nf * 16 + l15;
        size_t off = ((size_t)tt << 8) + o;
        float fx = acc[mf][nf][j] + brv[nf];
        float xn = xo_pre[mf][j][nf] + fx;
        xBf[off] = xn;
        xBb[off] = f2bf(xn);
        if (tt == 1023) fxs_i[(size_t)b * 256 + o] = fx;
      }
    }
}

// ---------------- head ----------------
__global__ __launch_bounds__(128) void skip_partial(
    const float* __restrict__ fxs, const float* __restrict__ wskT,
    const float* __restrict__ b_skip, float* __restrict__ part)
{
  int i = blockIdx.x, b = blockIdx.y, s = threadIdx.x;
  __shared__ float fxsh[256];
  fxsh[s]       = fxs[((size_t)i * 16 + b) * 256 + s];
  fxsh[s + 128] = fxs[((size_t)i * 16 + b) * 256 + s + 128];
  __syncthreads();
  float a = b_skip[i * 128 + s];
  const float* wp = wskT + (size_t)i * 256 * 128 + s;
  #pragma unroll 4
  for (int c = 0; c < 256; c++)
    a = fmaf(wp[c * 128], fxsh[c], a);
  part[((size_t)i * 16 + b) * 128 + s] = a;
}

__global__ __launch_bounds__(128) void head2(
    const float* __restrict__ part, const float* __restrict__ w_o1,
    const float* __restrict__ b_o1, const float* __restrict__ w_o2,
    const float* __restrict__ b_o2, const float* __restrict__ w_lin,
    const float* __restrict__ b_lin, const float* __restrict__ Xex,
    float* __restrict__ out)
{
  int b = blockIdx.x, tid = threadIdx.x;
  __shared__ float sk[128];
  __shared__ float h1[64];
  __shared__ float hc[80];
  float a = 0.f;
  for (int i = 0; i < 32; i++) a += part[((size_t)i * 16 + b) * 128 + tid];
  sk[tid] = fmaxf(a, 0.f);
  __syncthreads();
  if (tid < 64) {
    float a1 = b_o1[tid];
    for (int s = 0; s < 128; s++) a1 = fmaf(w_o1[tid * 128 + s], sk[s], a1);
    h1[tid] = fmaxf(a1, 0.f);
  }
  __syncthreads();
  if (tid < 64) {
    float a2 = b_o2[tid];
    for (int j = 0; j < 64; j++) a2 = fmaf(w_o2[tid * 64 + j], h1[j], a2);
    hc[tid] = fmaxf(a2, 0.f);
  }
  if (tid >= 64 && tid < 80) hc[tid] = fmaxf(Xex[b * 16 + (tid - 64)], 0.f);
  __syncthreads();
  if (tid < 24) {
    float a3 = b_lin[tid];
    for (int j = 0; j < 80; j++) a3 = fmaf(w_lin[tid * 80 + j], hc[j], a3);
    out[b * 24 + tid] = a3;
  }
}

extern "C" void kernel_launch(void* const* d_in, const int* in_sizes, int n_in,
                              void* d_out, int out_size, void* d_ws, size_t ws_size,
                              hipStream_t stream)
{
  (void)in_sizes; (void)n_in; (void)out_size; (void)ws_size;
  const float* X     = (const float*)d_in[0];
  const float* Xex   = (const float*)d_in[1];
  const float* w_in  = (const float*)d_in[2];
  const float* b_in  = (const float*)d_in[3];
  const float* w_f   = (const float*)d_in[4];
  const float* b_f   = (const float*)d_in[5];
  const float* w_g   = (const float*)d_in[6];
  const float* b_g   = (const float*)d_in[7];
  const float* w_r   = (const float*)d_in[8];
  const float* b_r   = (const float*)d_in[9];
  const float* w_s   = (const float*)d_in[10];
  const float* b_s   = (const float*)d_in[11];
  const float* w_o1  = (const float*)d_in[12];
  const float* b_o1  = (const float*)d_in[13];
  const float* w_o2  = (const float*)d_in[14];
  const float* b_o2  = (const float*)d_in[15];
  const float* w_lin = (const float*)d_in[16];
  const float* b_lin = (const float*)d_in[17];

  float* ws   = (float*)d_ws;
  float* wskT = ws;                        // 1,048,576 f
  float* xb   = wskT + 1048576;            // 4,194,304 f
  float* fxs  = xb   + 4194304;            // 131,072 f
  float* part = fxs  + 131072;             // 65,536 f
  float* w2   = part + 65536;              // 16,384 f
  unsigned short* Wb   = (unsigned short*)(w2 + 16384);    // 8,388,608 us
  unsigned short* Wrb  = Wb   + 8388608;   // 2,097,152 us
  unsigned short* xbbA = Wrb  + 2097152;   // 4,194,304 us
  unsigned short* xbbB = xbbA + 4194304;   // 4,194,304 us

  transform_fgb <<<16384, 256, 0, stream>>>(w_f, w_g, Wb);
  transform_resb<<<2048,  256, 0, stream>>>(w_r, Wrb);
  transform_skip<<<4096,  256, 0, stream>>>(w_s, wskT);
  transform_w2  <<<64,    256, 0, stream>>>(w_in, w2);
  in_conv<<<1024, 256, 0, stream>>>(X, w2, b_in, xb, xbbA);

  // suffix-window sizes: w[i] = w[i+1] + 2^(i%8), w[32] = 1
  static const int wI[33] = {1021,1020,1018,1014,1006,990,958,894,
                             766,765,763,759,751,735,703,639,
                             511,510,508,504,496,480,448,384,
                             256,255,253,249,241,225,193,129,1};
  for (int i = 0; i < 32; i++) {
    int dd    = 1 << (i & 7);
    int Wout  = wI[i + 1];
    int t_lo  = TBUF - Wout;
    int tiles = (Wout + 63) / 64;
    unsigned short* xin  = (i & 1) ? xbbB : xbbA;
    unsigned short* xout = (i & 1) ? xbbA : xbbB;
    layer_fused<<<tiles * 16, 512, 0, stream>>>(
        xin, xb, xout,
        Wb + (size_t)i * 512 * 512, Wrb + (size_t)i * 256 * 256,
        b_f + i * 256, b_g + i * 256, b_r + i * 256,
        dd, t_lo, fxs + (size_t)i * 16 * 256);
  }
  skip_partial<<<dim3(32, 16), 128, 0, stream>>>(fxs, wskT, b_s, part);
  head2<<<16, 128, 0, stream>>>(part, w_o1, b_o1, w_o2, b_o2, w_lin, b_lin, Xex, (float*)d_out);
}